// Round 1
// baseline (36.706 us; speedup 1.0000x reference)
//
#include <hip/hip_runtime.h>
#include <math.h>

#define NQ 4
#define NL 6
#define BATCH 524288
#define EPT 4  // elements per thread in main kernel

struct C2 { float re, im; };

__device__ __forceinline__ C2 cmul(C2 a, C2 b) {
    return C2{ __builtin_fmaf(a.re, b.re, -a.im * b.im),
               __builtin_fmaf(a.re, b.im,  a.im * b.re) };
}
__device__ __forceinline__ C2 cadd(C2 a, C2 b) { return C2{a.re + b.re, a.im + b.im}; }

// ---------------------------------------------------------------------------
// Prep kernel: 16 threads. Thread j evolves basis state e_j through the whole
// circuit (CNOT ladder + fused RZ*RY*RX per qubit per layer), multiplies the
// resulting column by (-i)^popcount(j) (folding the AngleEmbedding phases),
// and stores V[r][j] as interleaved (re,im) at ws[(r*16+j)*2 + {0,1}].
// ---------------------------------------------------------------------------
__global__ __launch_bounds__(64) void prep_kernel(const float* __restrict__ w,
                                                  float* __restrict__ V) {
    int j = threadIdx.x;
    if (j >= 16) return;

    C2 st[16];
#pragma unroll
    for (int n = 0; n < 16; ++n) st[n] = C2{0.f, 0.f};
    st[j].re = 1.f;

#define CSWAP(a, b) { C2 t_ = st[(a)]; st[(a)] = st[(b)]; st[(b)] = t_; }
#define CNOT(mc, mt)                                         \
    _Pragma("unroll")                                        \
    for (int n = 0; n < 16; ++n)                             \
        if ((n & (mc)) && !(n & (mt))) CSWAP(n, n ^ (mt));

#pragma unroll
    for (int l = 0; l < NL; ++l) {
        // CNOTs (0,1),(1,2),(2,3),(3,0); qubit q has mask 8>>q
        CNOT(8, 4)
        CNOT(4, 2)
        CNOT(2, 1)
        CNOT(1, 8)
#pragma unroll
        for (int q = 0; q < NQ; ++q) {
            const float a = w[(l * NQ + q) * 3 + 0];
            const float b = w[(l * NQ + q) * 3 + 1];
            const float g = w[(l * NQ + q) * 3 + 2];
            float ca, sa, cb, sb, cg, sg;
            sincosf(0.5f * a, &sa, &ca);
            sincosf(0.5f * b, &sb, &cb);
            sincosf(0.5f * g, &sg, &cg);
            // M = RY*RX
            C2 M00{cb * ca,  sb * sa};
            C2 M01{-sb * ca, -cb * sa};
            C2 M10{sb * ca,  -cb * sa};
            C2 M11{cb * ca,  -sb * sa};
            // U = RZ * M  (row0 *= e^{-ig/2}, row1 *= e^{+ig/2})
            C2 em{cg, -sg}, ep{cg, sg};
            C2 U00 = cmul(em, M00), U01 = cmul(em, M01);
            C2 U10 = cmul(ep, M10), U11 = cmul(ep, M11);
            const int m = 8 >> q;
#pragma unroll
            for (int n = 0; n < 16; ++n) {
                if (!(n & m)) {
                    C2 a0 = st[n], a1 = st[n | m];
                    st[n]     = cadd(cmul(U00, a0), cmul(U01, a1));
                    st[n | m] = cadd(cmul(U10, a0), cmul(U11, a1));
                }
            }
        }
    }

    // multiply column by (-i)^popcount(j): 0->(1,0) 1->(0,-1) 2->(-1,0) 3->(0,1)
    int p4 = __popc(j) & 3;
    float fr = (p4 == 0) ? 1.f : (p4 == 2) ? -1.f : 0.f;
    float fi = (p4 == 1) ? -1.f : (p4 == 3) ? 1.f : 0.f;
#pragma unroll
    for (int r = 0; r < 16; ++r) {
        float re = st[r].re * fr - st[r].im * fi;
        float im = st[r].re * fi + st[r].im * fr;
        V[(r * 16 + j) * 2 + 0] = re;
        V[(r * 16 + j) * 2 + 1] = im;
    }
#undef CSWAP
#undef CNOT
}

// ---------------------------------------------------------------------------
// Main kernel: each thread handles EPT=4 batch elements (strided by 256 for
// coalescing). psi_out = V * m with m real; ev_q = sum_r z_q(r) |psi_out_r|^2.
// ---------------------------------------------------------------------------
__global__ __launch_bounds__(256) void qmain_kernel(const float4* __restrict__ x,
                                                    const float* __restrict__ V,
                                                    float4* __restrict__ out) {
    __shared__ float4 sV4[128];  // 16 rows x 8 float4 (each float4 = 2 cols' re,im)
    const int tid = threadIdx.x;
    if (tid < 128) sV4[tid] = reinterpret_cast<const float4*>(V)[tid];
    __syncthreads();

    const int base = blockIdx.x * (256 * EPT) + tid;

    float m[EPT][16];
#pragma unroll
    for (int e = 0; e < EPT; ++e) {
        float4 xv = x[base + e * 256];
        float c0, s0, c1, s1, c2, s2, c3, s3;
        __sincosf(0.5f * xv.x, &s0, &c0);
        __sincosf(0.5f * xv.y, &s1, &c1);
        __sincosf(0.5f * xv.z, &s2, &c2);
        __sincosf(0.5f * xv.w, &s3, &c3);
        // product tree: n = b0*8 + b1*4 + b2*2 + b3
        float ab[4];
        ab[0] = c0 * c1; ab[1] = c0 * s1; ab[2] = s0 * c1; ab[3] = s0 * s1;
        float abc[8];
#pragma unroll
        for (int k = 0; k < 4; ++k) { abc[2 * k] = ab[k] * c2; abc[2 * k + 1] = ab[k] * s2; }
#pragma unroll
        for (int k = 0; k < 8; ++k) { m[e][2 * k] = abc[k] * c3; m[e][2 * k + 1] = abc[k] * s3; }
    }

    float ev[EPT][4];
#pragma unroll
    for (int e = 0; e < EPT; ++e)
#pragma unroll
        for (int q = 0; q < 4; ++q) ev[e][q] = 0.f;

#pragma unroll
    for (int r = 0; r < 16; ++r) {
        float4 row[8];
#pragma unroll
        for (int k = 0; k < 8; ++k) row[k] = sV4[r * 8 + k];
#pragma unroll
        for (int e = 0; e < EPT; ++e) {
            float re = 0.f, im = 0.f;
#pragma unroll
            for (int k = 0; k < 8; ++k) {
                re = __builtin_fmaf(m[e][2 * k],     row[k].x, re);
                im = __builtin_fmaf(m[e][2 * k],     row[k].y, im);
                re = __builtin_fmaf(m[e][2 * k + 1], row[k].z, re);
                im = __builtin_fmaf(m[e][2 * k + 1], row[k].w, im);
            }
            float p = __builtin_fmaf(re, re, im * im);
            if (r & 8) ev[e][0] -= p; else ev[e][0] += p;
            if (r & 4) ev[e][1] -= p; else ev[e][1] += p;
            if (r & 2) ev[e][2] -= p; else ev[e][2] += p;
            if (r & 1) ev[e][3] -= p; else ev[e][3] += p;
        }
    }

#pragma unroll
    for (int e = 0; e < EPT; ++e) {
        out[base + e * 256] = make_float4(ev[e][0], ev[e][1], ev[e][2], ev[e][3]);
    }
}

extern "C" void kernel_launch(void* const* d_in, const int* in_sizes, int n_in,
                              void* d_out, int out_size, void* d_ws, size_t ws_size,
                              hipStream_t stream) {
    const float4* x = (const float4*)d_in[0];          // [B,4] f32
    const float*  w = (const float*)d_in[1];           // [6,4,3] f32
    float* V = (float*)d_ws;                           // 16*16*2 floats = 2 KB
    float4* out = (float4*)d_out;                      // [B,4] f32

    prep_kernel<<<1, 64, 0, stream>>>(w, V);
    const int blocks = BATCH / (256 * EPT);            // 512
    qmain_kernel<<<blocks, 256, 0, stream>>>(x, V, out);
}

// Round 2
// 28.790 us; speedup vs baseline: 1.2750x; 1.2750x over previous
//
#include <hip/hip_runtime.h>
#include <math.h>

#define NQ 4
#define NL 6
#define BATCH 524288
#define EPT 4  // elements per thread in main kernel

struct C2 { float re, im; };

__device__ __forceinline__ C2 cmul(C2 a, C2 b) {
    return C2{ __builtin_fmaf(a.re, b.re, -a.im * b.im),
               __builtin_fmaf(a.re, b.im,  a.im * b.re) };
}

// ---------------------------------------------------------------------------
// Prep kernel (parallelized): 1 block, 64 threads.
// Phase 1: lanes 0..23 each compute one fused U = RZ*RY*RX 2x2 gate -> LDS.
// Phase 2: lanes 0..31; lane = 2*j + h (column j of the 16x16 unitary,
//          h = bit3 of row). Each lane carries 8 complex amplitudes
//          st[i] = psi[h*8+i] of basis-column j evolved through the circuit.
//          Cross-half ops (qubit-0 gate, CNOT(3->0), CNOT(0->1)) use
//          __shfl_xor(...,1); the rest are register-local.
// Finally multiplies column j by (-i)^popcount(j) (folds the AngleEmbedding
// phases) and stores V[r][j] interleaved (re,im) at V[(r*16+j)*2 + {0,1}].
// ---------------------------------------------------------------------------
__global__ __launch_bounds__(64) void prep_kernel(const float* __restrict__ w,
                                                  float* __restrict__ V) {
    __shared__ float sU[NL * NQ * 8];
    const int lane = threadIdx.x;

    // ---- Phase 1: build all 24 fused gate matrices in parallel ----
    if (lane < NL * NQ) {
        const float a = w[lane * 3 + 0];
        const float b = w[lane * 3 + 1];
        const float g = w[lane * 3 + 2];
        float ca, sa, cb, sb, cg, sg;
        sincosf(0.5f * a, &sa, &ca);
        sincosf(0.5f * b, &sb, &cb);
        sincosf(0.5f * g, &sg, &cg);
        // M = RY*RX
        C2 M00{cb * ca,  sb * sa};
        C2 M01{-sb * ca, -cb * sa};
        C2 M10{sb * ca,  -cb * sa};
        C2 M11{cb * ca,  -sb * sa};
        // U = RZ * M
        C2 em{cg, -sg}, ep{cg, sg};
        C2 U00 = cmul(em, M00), U01 = cmul(em, M01);
        C2 U10 = cmul(ep, M10), U11 = cmul(ep, M11);
        float* o = &sU[lane * 8];
        o[0] = U00.re; o[1] = U00.im; o[2] = U01.re; o[3] = U01.im;
        o[4] = U10.re; o[5] = U10.im; o[6] = U11.re; o[7] = U11.im;
    }
    __syncthreads();

    // ---- Phase 2: evolve basis columns, 2 lanes per column ----
    if (lane >= 32) return;
    const int j = lane >> 1;   // column (initial basis state)
    const int h = lane & 1;    // bit3 of the rows this lane owns

    C2 st[8];
#pragma unroll
    for (int i = 0; i < 8; ++i) st[i] = C2{0.f, 0.f};
    if ((j >> 3) == h) st[j & 7].re = 1.f;

#define APPLY_PAIR(i0, i1)                                                     \
    {                                                                          \
        C2 a0 = st[i0], a1 = st[i1];                                           \
        st[i0].re = U00.re*a0.re - U00.im*a0.im + U01.re*a1.re - U01.im*a1.im; \
        st[i0].im = U00.re*a0.im + U00.im*a0.re + U01.re*a1.im + U01.im*a1.re; \
        st[i1].re = U10.re*a0.re - U10.im*a0.im + U11.re*a1.re - U11.im*a1.im; \
        st[i1].im = U10.re*a0.im + U10.im*a0.re + U11.re*a1.im + U11.im*a1.re; \
    }
#define SWAPST(a, b) { C2 t_ = st[a]; st[a] = st[b]; st[b] = t_; }

#pragma unroll
    for (int l = 0; l < NL; ++l) {
        // CNOT(ctrl=q0 mask8, tgt=q1 mask4): if h==1, swap i <-> i^4
        {
            C2 ns[8];
#pragma unroll
            for (int i = 0; i < 8; ++i) {
                ns[i].re = h ? st[i ^ 4].re : st[i].re;
                ns[i].im = h ? st[i ^ 4].im : st[i].im;
            }
#pragma unroll
            for (int i = 0; i < 8; ++i) st[i] = ns[i];
        }
        // CNOT(q1 mask4, q2 mask2): if i&4: swap i <-> i^2
        SWAPST(4, 6) SWAPST(5, 7)
        // CNOT(q2 mask2, q3 mask1): if i&2: swap i <-> i^1
        SWAPST(2, 3) SWAPST(6, 7)
        // CNOT(q3 mask1, q0 mask8): odd rows exchange across halves
#pragma unroll
        for (int i = 1; i < 8; i += 2) {
            st[i].re = __shfl_xor(st[i].re, 1);
            st[i].im = __shfl_xor(st[i].im, 1);
        }

        // qubit 0 gate (mask 8): cross-lane
        {
            const float* u = &sU[(l * NQ + 0) * 8];
            C2 U00{u[0], u[1]}, U01{u[2], u[3]}, U10{u[4], u[5]}, U11{u[6], u[7]};
            C2 Ud = h ? U11 : U00;
            C2 Uo = h ? U10 : U01;
#pragma unroll
            for (int i = 0; i < 8; ++i) {
                C2 p{__shfl_xor(st[i].re, 1), __shfl_xor(st[i].im, 1)};
                C2 a = st[i];
                st[i].re = Ud.re*a.re - Ud.im*a.im + Uo.re*p.re - Uo.im*p.im;
                st[i].im = Ud.re*a.im + Ud.im*a.re + Uo.re*p.im + Uo.im*p.re;
            }
        }
        // qubit 1 gate (mask 4): in-lane pairs
        {
            const float* u = &sU[(l * NQ + 1) * 8];
            C2 U00{u[0], u[1]}, U01{u[2], u[3]}, U10{u[4], u[5]}, U11{u[6], u[7]};
            APPLY_PAIR(0, 4) APPLY_PAIR(1, 5) APPLY_PAIR(2, 6) APPLY_PAIR(3, 7)
        }
        // qubit 2 gate (mask 2)
        {
            const float* u = &sU[(l * NQ + 2) * 8];
            C2 U00{u[0], u[1]}, U01{u[2], u[3]}, U10{u[4], u[5]}, U11{u[6], u[7]};
            APPLY_PAIR(0, 2) APPLY_PAIR(1, 3) APPLY_PAIR(4, 6) APPLY_PAIR(5, 7)
        }
        // qubit 3 gate (mask 1)
        {
            const float* u = &sU[(l * NQ + 3) * 8];
            C2 U00{u[0], u[1]}, U01{u[2], u[3]}, U10{u[4], u[5]}, U11{u[6], u[7]};
            APPLY_PAIR(0, 1) APPLY_PAIR(2, 3) APPLY_PAIR(4, 5) APPLY_PAIR(6, 7)
        }
    }

    // phase (-i)^popcount(j): 0->(1,0) 1->(0,-1) 2->(-1,0) 3->(0,1)
    const int p4 = __popc(j) & 3;
    const float fr = (p4 == 0) ? 1.f : (p4 == 2) ? -1.f : 0.f;
    const float fi = (p4 == 1) ? -1.f : (p4 == 3) ? 1.f : 0.f;
#pragma unroll
    for (int i = 0; i < 8; ++i) {
        const int r = h * 8 + i;
        float re = st[i].re * fr - st[i].im * fi;
        float im = st[i].re * fi + st[i].im * fr;
        V[(r * 16 + j) * 2 + 0] = re;
        V[(r * 16 + j) * 2 + 1] = im;
    }
#undef APPLY_PAIR
#undef SWAPST
}

// ---------------------------------------------------------------------------
// Main kernel: each thread handles EPT=4 batch elements (strided by 256 for
// coalescing). psi_out = V * m with m real; ev_q = sum_r z_q(r) |psi_out_r|^2.
// ---------------------------------------------------------------------------
__global__ __launch_bounds__(256) void qmain_kernel(const float4* __restrict__ x,
                                                    const float* __restrict__ V,
                                                    float4* __restrict__ out) {
    __shared__ float4 sV4[128];  // 16 rows x 8 float4 (each float4 = 2 cols' re,im)
    const int tid = threadIdx.x;
    if (tid < 128) sV4[tid] = reinterpret_cast<const float4*>(V)[tid];
    __syncthreads();

    const int base = blockIdx.x * (256 * EPT) + tid;

    float m[EPT][16];
#pragma unroll
    for (int e = 0; e < EPT; ++e) {
        float4 xv = x[base + e * 256];
        float c0, s0, c1, s1, c2, s2, c3, s3;
        __sincosf(0.5f * xv.x, &s0, &c0);
        __sincosf(0.5f * xv.y, &s1, &c1);
        __sincosf(0.5f * xv.z, &s2, &c2);
        __sincosf(0.5f * xv.w, &s3, &c3);
        float ab[4];
        ab[0] = c0 * c1; ab[1] = c0 * s1; ab[2] = s0 * c1; ab[3] = s0 * s1;
        float abc[8];
#pragma unroll
        for (int k = 0; k < 4; ++k) { abc[2 * k] = ab[k] * c2; abc[2 * k + 1] = ab[k] * s2; }
#pragma unroll
        for (int k = 0; k < 8; ++k) { m[e][2 * k] = abc[k] * c3; m[e][2 * k + 1] = abc[k] * s3; }
    }

    float ev[EPT][4];
#pragma unroll
    for (int e = 0; e < EPT; ++e)
#pragma unroll
        for (int q = 0; q < 4; ++q) ev[e][q] = 0.f;

#pragma unroll
    for (int r = 0; r < 16; ++r) {
        float4 row[8];
#pragma unroll
        for (int k = 0; k < 8; ++k) row[k] = sV4[r * 8 + k];
#pragma unroll
        for (int e = 0; e < EPT; ++e) {
            float re = 0.f, im = 0.f;
#pragma unroll
            for (int k = 0; k < 8; ++k) {
                re = __builtin_fmaf(m[e][2 * k],     row[k].x, re);
                im = __builtin_fmaf(m[e][2 * k],     row[k].y, im);
                re = __builtin_fmaf(m[e][2 * k + 1], row[k].z, re);
                im = __builtin_fmaf(m[e][2 * k + 1], row[k].w, im);
            }
            float p = __builtin_fmaf(re, re, im * im);
            if (r & 8) ev[e][0] -= p; else ev[e][0] += p;
            if (r & 4) ev[e][1] -= p; else ev[e][1] += p;
            if (r & 2) ev[e][2] -= p; else ev[e][2] += p;
            if (r & 1) ev[e][3] -= p; else ev[e][3] += p;
        }
    }

#pragma unroll
    for (int e = 0; e < EPT; ++e) {
        out[base + e * 256] = make_float4(ev[e][0], ev[e][1], ev[e][2], ev[e][3]);
    }
}

extern "C" void kernel_launch(void* const* d_in, const int* in_sizes, int n_in,
                              void* d_out, int out_size, void* d_ws, size_t ws_size,
                              hipStream_t stream) {
    const float4* x = (const float4*)d_in[0];          // [B,4] f32
    const float*  w = (const float*)d_in[1];           // [6,4,3] f32
    float* V = (float*)d_ws;                           // 16*16*2 floats = 2 KB
    float4* out = (float4*)d_out;                      // [B,4] f32

    prep_kernel<<<1, 64, 0, stream>>>(w, V);
    const int blocks = BATCH / (256 * EPT);            // 512
    qmain_kernel<<<blocks, 256, 0, stream>>>(x, V, out);
}